// Round 1
// baseline (899.233 us; speedup 1.0000x reference)
//
#include <hip/hip_runtime.h>
#include <hip/hip_bf16.h>

#define F 128

// ---------------- CSR build ----------------

__global__ void count_edges_k(const int* __restrict__ col, int* __restrict__ cnt, int E) {
    int e = blockIdx.x * 256 + threadIdx.x;
    if (e < E) atomicAdd(&cnt[col[e]], 1);
}

// per-block exclusive scan (1024), block sums out
__global__ void scan1_k(const int* __restrict__ cnt, int* __restrict__ offs,
                        float* __restrict__ dinv, int* __restrict__ bsum, int n) {
    __shared__ int s[1024];
    int tid = threadIdx.x;
    int i = blockIdx.x * 1024 + tid;
    int v = (i < n) ? cnt[i] : 0;
    s[tid] = v;
    __syncthreads();
    for (int off = 1; off < 1024; off <<= 1) {
        int t = (tid >= off) ? s[tid - off] : 0;
        __syncthreads();
        s[tid] += t;
        __syncthreads();
    }
    if (i < n) {
        offs[i] = s[tid] - v;                    // exclusive within block
        dinv[i] = rsqrtf((float)(v + 1));        // deg includes self-loop
    }
    if (tid == 1023) bsum[blockIdx.x] = s[1023];
}

// scan block sums (assumes nb <= 128)
__global__ void scan2_k(int* bsum, int nb) {
    __shared__ int s[128];
    int tid = threadIdx.x;
    int v = (tid < nb) ? bsum[tid] : 0;
    s[tid] = v;
    __syncthreads();
    for (int off = 1; off < 128; off <<= 1) {
        int t = (tid >= off) ? s[tid - off] : 0;
        __syncthreads();
        s[tid] += t;
        __syncthreads();
    }
    if (tid < nb) bsum[tid] = s[tid] - v;        // exclusive
}

__global__ void scan3_k(int* __restrict__ offs, int* __restrict__ cursor,
                        const int* __restrict__ bsum, int n, int E) {
    int i = blockIdx.x * 1024 + threadIdx.x;
    if (i < n) {
        int o = offs[i] + bsum[blockIdx.x];
        offs[i] = o;
        cursor[i] = o;
    }
    if (i == n) offs[n] = E;
}

__global__ void fill_k(const int* __restrict__ row, const int* __restrict__ col,
                       int* __restrict__ cursor, int* __restrict__ src, int E) {
    int e = blockIdx.x * 256 + threadIdx.x;
    if (e < E) {
        int v = col[e];
        int pos = atomicAdd(&cursor[v], 1);
        src[pos] = row[e];
    }
}

// ---------------- GEMM: Y[r,:] = dinv[r] * (X[r,:] @ W), 128x128 W in LDS ----------------
// block = 256 threads, 64 rows/block (8 row-groups x 8 rows/thread), 4 cols/thread

__global__ __launch_bounds__(256) void gemm_scale_k(const float* __restrict__ X,
                                                    const float* __restrict__ W,
                                                    const float* __restrict__ dinv,
                                                    float* __restrict__ Y, int n) {
    __shared__ float Ws[F * F];   // 64 KB
    for (int i = threadIdx.x; i < F * F; i += 256) Ws[i] = W[i];
    __syncthreads();

    int lane = threadIdx.x & 31;
    int rg = threadIdx.x >> 5;            // 0..7
    int jc = lane * 4;                    // output col group
    int r0 = blockIdx.x * 64 + rg * 8;

    float4 acc[8];
#pragma unroll
    for (int i = 0; i < 8; i++) acc[i] = make_float4(0.f, 0.f, 0.f, 0.f);

    const float* xbase[8];
#pragma unroll
    for (int i = 0; i < 8; i++) {
        int r = r0 + i;
        if (r > n - 1) r = n - 1;         // clamp loads, guard stores
        xbase[i] = X + (size_t)r * F;
    }

    for (int k = 0; k < F; k++) {
        float4 w = *(const float4*)&Ws[k * F + jc];
#pragma unroll
        for (int i = 0; i < 8; i++) {
            float xv = xbase[i][k];
            acc[i].x = fmaf(xv, w.x, acc[i].x);
            acc[i].y = fmaf(xv, w.y, acc[i].y);
            acc[i].z = fmaf(xv, w.z, acc[i].z);
            acc[i].w = fmaf(xv, w.w, acc[i].w);
        }
    }

#pragma unroll
    for (int i = 0; i < 8; i++) {
        int r = r0 + i;
        if (r < n) {
            float s = dinv[r];
            float4 o = make_float4(s * acc[i].x, s * acc[i].y, s * acc[i].z, s * acc[i].w);
            *(float4*)&Y[(size_t)r * F + jc] = o;
        }
    }
}

// ---------------- Aggregation: h[v] = relu(dinv[v]*(y[v] + sum_{u in N(v)} y[u]) + b) -------
// 32 lanes per node (float4 each = 128 feats). WRITE_H=1: store h. WRITE_H=0: pool into gacc.

template <int WRITE_H>
__global__ __launch_bounds__(256) void agg_k(const float4* __restrict__ Y4,
                                             const float* __restrict__ dinv,
                                             const int* __restrict__ offs,
                                             const int* __restrict__ src,
                                             const float* __restrict__ bias,
                                             float4* __restrict__ H4,
                                             float* __restrict__ gacc, int n) {
    int g = blockIdx.x * 8 + (threadIdx.x >> 5);   // node
    int lane = threadIdx.x & 31;

    float4 acc = make_float4(0.f, 0.f, 0.f, 0.f);
    float dv = 0.f;
    if (g < n) {
        acc = Y4[(size_t)g * 32 + lane];           // self-loop term
        int s = offs[g], e = offs[g + 1];
        for (int i = s; i < e; i++) {
            int u = src[i];
            float4 t = Y4[(size_t)u * 32 + lane];
            acc.x += t.x; acc.y += t.y; acc.z += t.z; acc.w += t.w;
        }
        dv = dinv[g];
    }

    float4 b = ((const float4*)bias)[lane];
    float4 h;
    h.x = fmaxf(fmaf(dv, acc.x, b.x), 0.f);
    h.y = fmaxf(fmaf(dv, acc.y, b.y), 0.f);
    h.z = fmaxf(fmaf(dv, acc.z, b.z), 0.f);
    h.w = fmaxf(fmaf(dv, acc.w, b.w), 0.f);

    if (WRITE_H) {
        if (g < n) H4[(size_t)g * 32 + lane] = h;
    } else {
        if (g >= n) h = make_float4(0.f, 0.f, 0.f, 0.f);
        __shared__ float4 red[256];
        red[threadIdx.x] = h;
        __syncthreads();
        if (threadIdx.x < 128) {
            int l = threadIdx.x >> 2, c = threadIdx.x & 3;
            float ssum = 0.f;
#pragma unroll
            for (int gg = 0; gg < 8; gg++) {
                const float* rp = (const float*)&red[gg * 32 + l];
                ssum += rp[c];
            }
            atomicAdd(&gacc[threadIdx.x], ssum);   // feature index == threadIdx.x
        }
    }
}

// ---------------- Final: out[a] = sum_k (gacc[k]/N) * Wl[k][a] + bl[a] ----------------

__global__ void final_k(const float* __restrict__ gacc, const float* __restrict__ Wl,
                        const float* __restrict__ bl, float* __restrict__ out, float invN) {
    int a = threadIdx.x;
    if (a < 16) {
        float s = bl[a];
        for (int k = 0; k < 128; k++) s = fmaf(gacc[k] * invN, Wl[k * 16 + a], s);
        out[a] = s;
    }
}

extern "C" void kernel_launch(void* const* d_in, const int* in_sizes, int n_in,
                              void* d_out, int out_size, void* d_ws, size_t ws_size,
                              hipStream_t stream) {
    const float* x  = (const float*)d_in[0];
    const int*   ei = (const int*)d_in[1];
    const float* W1 = (const float*)d_in[2];
    const float* b1 = (const float*)d_in[3];
    const float* W2 = (const float*)d_in[4];
    const float* b2 = (const float*)d_in[5];
    const float* Wl = (const float*)d_in[6];
    const float* bl = (const float*)d_in[7];

    int N = in_sizes[0] / F;
    int E = in_sizes[1] / 2;
    const int* row = ei;
    const int* col = ei + E;

    char* ws = (char*)d_ws;
    size_t off = 0;
    auto alloc = [&](size_t bytes) -> void* {
        void* p = ws + off;
        off = (off + bytes + 255) & ~(size_t)255;
        return p;
    };
    int*   cnt    = (int*)  alloc((size_t)N * 4);
    int*   offs   = (int*)  alloc((size_t)(N + 1) * 4);
    int*   cursor = (int*)  alloc((size_t)N * 4);
    float* dinv   = (float*)alloc((size_t)N * 4);
    int*   bsum   = (int*)  alloc(1024 * 4);
    int*   srcb   = (int*)  alloc((size_t)E * 4);
    float* y      = (float*)alloc((size_t)N * F * 4);
    float* h      = (float*)alloc((size_t)N * F * 4);
    float* gacc   = (float*)alloc(128 * 4);

    hipMemsetAsync(cnt, 0, (size_t)N * 4, stream);
    hipMemsetAsync(gacc, 0, 128 * 4, stream);

    int NB = (N + 1023) / 1024;
    count_edges_k<<<(E + 255) / 256, 256, 0, stream>>>(col, cnt, E);
    scan1_k<<<NB, 1024, 0, stream>>>(cnt, offs, dinv, bsum, N);
    scan2_k<<<1, 128, 0, stream>>>(bsum, NB);
    scan3_k<<<(N + 1024) / 1024, 1024, 0, stream>>>(offs, cursor, bsum, N, E);
    fill_k<<<(E + 255) / 256, 256, 0, stream>>>(row, col, cursor, srcb, E);

    gemm_scale_k<<<(N + 63) / 64, 256, 0, stream>>>(x, W1, dinv, y, N);
    agg_k<1><<<(N + 7) / 8, 256, 0, stream>>>((const float4*)y, dinv, offs, srcb, b1, (float4*)h, nullptr, N);
    gemm_scale_k<<<(N + 63) / 64, 256, 0, stream>>>(h, W2, dinv, y, N);
    agg_k<0><<<(N + 7) / 8, 256, 0, stream>>>((const float4*)y, dinv, offs, srcb, b2, nullptr, gacc, N);
    final_k<<<1, 64, 0, stream>>>(gacc, Wl, bl, (float*)d_out, 1.0f / (float)N);
}

// Round 2
// 580.560 us; speedup vs baseline: 1.5489x; 1.5489x over previous
//
#include <hip/hip_runtime.h>
#include <hip/hip_bf16.h>

#define F 128

static __device__ __forceinline__ unsigned short f2bf(float f) {
    unsigned int u = __float_as_uint(f);
    unsigned int r = (u + 0x7fffu + ((u >> 16) & 1u)) >> 16;   // RTN-even
    return (unsigned short)r;
}

// ---------------- CSR build ----------------

__global__ void count_edges_k(const int* __restrict__ col, int* __restrict__ cnt, int E) {
    int e = blockIdx.x * 256 + threadIdx.x;
    if (e < E) atomicAdd(&cnt[col[e]], 1);
}

__global__ void scan1_k(const int* __restrict__ cnt, int* __restrict__ offs,
                        float* __restrict__ dinv, int* __restrict__ bsum, int n) {
    __shared__ int s[1024];
    int tid = threadIdx.x;
    int i = blockIdx.x * 1024 + tid;
    int v = (i < n) ? cnt[i] : 0;
    s[tid] = v;
    __syncthreads();
    for (int off = 1; off < 1024; off <<= 1) {
        int t = (tid >= off) ? s[tid - off] : 0;
        __syncthreads();
        s[tid] += t;
        __syncthreads();
    }
    if (i < n) {
        offs[i] = s[tid] - v;
        dinv[i] = rsqrtf((float)(v + 1));
    }
    if (tid == 1023) bsum[blockIdx.x] = s[1023];
}

__global__ void scan2_k(int* bsum, int nb) {
    __shared__ int s[128];
    int tid = threadIdx.x;
    int v = (tid < nb) ? bsum[tid] : 0;
    s[tid] = v;
    __syncthreads();
    for (int off = 1; off < 128; off <<= 1) {
        int t = (tid >= off) ? s[tid - off] : 0;
        __syncthreads();
        s[tid] += t;
        __syncthreads();
    }
    if (tid < nb) bsum[tid] = s[tid] - v;
}

__global__ void scan3_k(int* __restrict__ offs, int* __restrict__ cursor,
                        const int* __restrict__ bsum, int n, int E) {
    int i = blockIdx.x * 1024 + threadIdx.x;
    if (i < n) {
        int o = offs[i] + bsum[blockIdx.x];
        offs[i] = o;
        cursor[i] = o;
    }
    if (i == n) offs[n] = E;
}

__global__ void fill_k(const int* __restrict__ row, const int* __restrict__ col,
                       int* __restrict__ cursor, int* __restrict__ src, int E) {
    int e = blockIdx.x * 256 + threadIdx.x;
    if (e < E) {
        int v = col[e];
        int pos = atomicAdd(&cursor[v], 1);
        src[pos] = row[e];
    }
}

// ---------------- GEMM: Ybf[r,:] = bf16( dinv[r] * (X[r,:] @ W) ) ----------------

__global__ __launch_bounds__(256) void gemm_scale_k(const float* __restrict__ X,
                                                    const float* __restrict__ W,
                                                    const float* __restrict__ dinv,
                                                    unsigned short* __restrict__ Ybf, int n) {
    __shared__ float Ws[F * F];   // 64 KB
    for (int i = threadIdx.x; i < F * F; i += 256) Ws[i] = W[i];
    __syncthreads();

    int lane = threadIdx.x & 31;
    int rg = threadIdx.x >> 5;
    int jc = lane * 4;
    int r0 = blockIdx.x * 64 + rg * 8;

    float4 acc[8];
#pragma unroll
    for (int i = 0; i < 8; i++) acc[i] = make_float4(0.f, 0.f, 0.f, 0.f);

    const float* xbase[8];
#pragma unroll
    for (int i = 0; i < 8; i++) {
        int r = r0 + i;
        if (r > n - 1) r = n - 1;
        xbase[i] = X + (size_t)r * F;
    }

    for (int k = 0; k < F; k++) {
        float4 w = *(const float4*)&Ws[k * F + jc];
#pragma unroll
        for (int i = 0; i < 8; i++) {
            float xv = xbase[i][k];
            acc[i].x = fmaf(xv, w.x, acc[i].x);
            acc[i].y = fmaf(xv, w.y, acc[i].y);
            acc[i].z = fmaf(xv, w.z, acc[i].z);
            acc[i].w = fmaf(xv, w.w, acc[i].w);
        }
    }

#pragma unroll
    for (int i = 0; i < 8; i++) {
        int r = r0 + i;
        if (r < n) {
            float s = dinv[r];
            ushort4 o;
            o.x = f2bf(s * acc[i].x);
            o.y = f2bf(s * acc[i].y);
            o.z = f2bf(s * acc[i].z);
            o.w = f2bf(s * acc[i].w);
            *(ushort4*)&Ybf[(size_t)r * F + jc] = o;
        }
    }
}

// ---------------- Aggregation: one 64-lane wave per node, grid-strided ----------------
// h[v] = relu(dinv[v]*(y[v] + sum_{u in N(v)} y[u]) + b)
// WRITE_H=1: store h (f32). WRITE_H=0: pool into gacc via register acc + block reduce.

#define BF2X(p) __uint_as_float((p) << 16)
#define BF2Y(p) __uint_as_float((p) & 0xffff0000u)

template <int WRITE_H>
__global__ __launch_bounds__(256) void agg_k(const unsigned short* __restrict__ Ybf,
                                             const float* __restrict__ dinv,
                                             const int* __restrict__ offs,
                                             const int* __restrict__ src,
                                             const float* __restrict__ bias,
                                             float* __restrict__ H,
                                             float* __restrict__ gacc,
                                             int n, int nwaves) {
    int lane = threadIdx.x & 63;
    int wid = (blockIdx.x * 256 + threadIdx.x) >> 6;   // global wave id
    int c = lane * 2;                                   // feature pair base

    float2 b = *(const float2*)&bias[c];
    float2 pacc = make_float2(0.f, 0.f);

    for (int g = wid; g < n; g += nwaves) {
        unsigned int ps = *(const unsigned int*)&Ybf[(size_t)g * F + c];   // self-loop
        float2 a0 = make_float2(BF2X(ps), BF2Y(ps));
        float2 a1 = make_float2(0.f, 0.f);

        int s = offs[g], e = offs[g + 1];
        int i = s;
        for (; i + 4 <= e; i += 4) {
            int u0 = src[i], u1 = src[i + 1], u2 = src[i + 2], u3 = src[i + 3];
            unsigned int p0 = *(const unsigned int*)&Ybf[(size_t)u0 * F + c];
            unsigned int p1 = *(const unsigned int*)&Ybf[(size_t)u1 * F + c];
            unsigned int p2 = *(const unsigned int*)&Ybf[(size_t)u2 * F + c];
            unsigned int p3 = *(const unsigned int*)&Ybf[(size_t)u3 * F + c];
            a0.x += BF2X(p0); a0.y += BF2Y(p0);
            a1.x += BF2X(p1); a1.y += BF2Y(p1);
            a0.x += BF2X(p2); a0.y += BF2Y(p2);
            a1.x += BF2X(p3); a1.y += BF2Y(p3);
        }
        for (; i < e; i++) {
            int u = src[i];
            unsigned int p0 = *(const unsigned int*)&Ybf[(size_t)u * F + c];
            a0.x += BF2X(p0); a0.y += BF2Y(p0);
        }

        float dv = dinv[g];
        float hx = fmaxf(fmaf(dv, a0.x + a1.x, b.x), 0.f);
        float hy = fmaxf(fmaf(dv, a0.y + a1.y, b.y), 0.f);

        if (WRITE_H) {
            *(float2*)&H[(size_t)g * F + c] = make_float2(hx, hy);
        } else {
            pacc.x += hx;
            pacc.y += hy;
        }
    }

    if (!WRITE_H) {
        __shared__ float2 red[256];
        red[threadIdx.x] = pacc;
        __syncthreads();
        if (threadIdx.x < 64) {
            float2 s0 = red[threadIdx.x];
            float2 s1 = red[64 + threadIdx.x];
            float2 s2 = red[128 + threadIdx.x];
            float2 s3 = red[192 + threadIdx.x];
            float sx = s0.x + s1.x + s2.x + s3.x;
            float sy = s0.y + s1.y + s2.y + s3.y;
            atomicAdd(&gacc[2 * threadIdx.x], sx);
            atomicAdd(&gacc[2 * threadIdx.x + 1], sy);
        }
    }
}

// ---------------- Final: out[a] = sum_k (gacc[k]/N) * Wl[k][a] + bl[a] ----------------

__global__ void final_k(const float* __restrict__ gacc, const float* __restrict__ Wl,
                        const float* __restrict__ bl, float* __restrict__ out, float invN) {
    int a = threadIdx.x;
    if (a < 16) {
        float s = bl[a];
        for (int k = 0; k < 128; k++) s = fmaf(gacc[k] * invN, Wl[k * 16 + a], s);
        out[a] = s;
    }
}

extern "C" void kernel_launch(void* const* d_in, const int* in_sizes, int n_in,
                              void* d_out, int out_size, void* d_ws, size_t ws_size,
                              hipStream_t stream) {
    const float* x  = (const float*)d_in[0];
    const int*   ei = (const int*)d_in[1];
    const float* W1 = (const float*)d_in[2];
    const float* b1 = (const float*)d_in[3];
    const float* W2 = (const float*)d_in[4];
    const float* b2 = (const float*)d_in[5];
    const float* Wl = (const float*)d_in[6];
    const float* bl = (const float*)d_in[7];

    int N = in_sizes[0] / F;
    int E = in_sizes[1] / 2;
    const int* row = ei;
    const int* col = ei + E;

    char* ws = (char*)d_ws;
    size_t off = 0;
    auto alloc = [&](size_t bytes) -> void* {
        void* p = ws + off;
        off = (off + bytes + 255) & ~(size_t)255;
        return p;
    };
    int*            cnt    = (int*)           alloc((size_t)N * 4);
    int*            offs   = (int*)           alloc((size_t)(N + 1) * 4);
    int*            cursor = (int*)           alloc((size_t)N * 4);
    float*          dinv   = (float*)         alloc((size_t)N * 4);
    int*            bsum   = (int*)           alloc(1024 * 4);
    int*            srcb   = (int*)           alloc((size_t)E * 4);
    unsigned short* ybf    = (unsigned short*)alloc((size_t)N * F * 2);
    float*          h      = (float*)         alloc((size_t)N * F * 4);
    float*          gacc   = (float*)         alloc(128 * 4);

    hipMemsetAsync(cnt, 0, (size_t)N * 4, stream);
    hipMemsetAsync(gacc, 0, 128 * 4, stream);

    int NB = (N + 1023) / 1024;
    count_edges_k<<<(E + 255) / 256, 256, 0, stream>>>(col, cnt, E);
    scan1_k<<<NB, 1024, 0, stream>>>(cnt, offs, dinv, bsum, N);
    scan2_k<<<1, 128, 0, stream>>>(bsum, NB);
    scan3_k<<<(N + 1024) / 1024, 1024, 0, stream>>>(offs, cursor, bsum, N, E);
    fill_k<<<(E + 255) / 256, 256, 0, stream>>>(row, col, cursor, srcb, E);

    const int AGG_BLOCKS = 2048;                 // 8 blocks/CU exactly
    const int NWAVES = AGG_BLOCKS * 4;

    gemm_scale_k<<<(N + 63) / 64, 256, 0, stream>>>(x, W1, dinv, ybf, N);
    agg_k<1><<<AGG_BLOCKS, 256, 0, stream>>>(ybf, dinv, offs, srcb, b1, h, nullptr, N, NWAVES);
    gemm_scale_k<<<(N + 63) / 64, 256, 0, stream>>>(h, W2, dinv, ybf, N);
    agg_k<0><<<AGG_BLOCKS, 256, 0, stream>>>(ybf, dinv, offs, srcb, b2, nullptr, gacc, N, NWAVES);
    final_k<<<1, 64, 0, stream>>>(gacc, Wl, bl, (float*)d_out, 1.0f / (float)N);
}